// Round 18
// baseline (218.152 us; speedup 1.0000x reference)
//
#include <hip/hip_runtime.h>

#define Nn 100000
#define Tt 16
#define Dd 8
#define Hh 40
#define HP1 41
#define XSD 51     // Xs row: [h0..h39, 1, x0..x7, y, 0pad] stride 51
#define PSD 20     // Ps row stride (floats): 80B, 16B-aligned, de-aliases banks
#define NPAIR 1275 // 50*51/2 symmetric pairs (i,j in [0,50))
#define NB 128
#define NTILES ((Nn + NB - 1) / NB)   // 782
#define SLAB 20480           // floats per block-slab (NPAIR*16 = 20400, padded)
#define MAXSLABS 784
#define SLABGRP 32           // slabs per stage-A group
#define MAXGRP ((MAXSLABS + SLABGRP - 1) / SLABGRP)   // 25
#define WS_ACC 0             // acc_red: 20480 floats
#define WS_PART 21504        // stage-A partials: MAXGRP * SLAB floats
#define WS_SLB (WS_PART + MAXGRP * SLAB)              // slabs start here

// output offsets (flat, return order)
#define OFF_BG1   0
#define OFF_BG2   16
#define OFF_MU    32
#define OFF_KAPPA 160
#define OFF_NU    176
#define OFF_PSI   192
#define OFF_WM    1216
#define OFF_WS    1872
#define OFF_ZA    28768
#define OFF_ZB    28784
#define OFF_EA    28800
#define OFF_EB    28816

typedef float v16f __attribute__((ext_vector_type(16)));

__device__ __forceinline__ int pidx(int i, int j) {
  if (i > j) { int tmp = i; i = j; j = tmp; }
  return (i * (2 * 50 - i + 1)) / 2 + (j - i);
}

__device__ __forceinline__ void fma16(v16f& A, float p, float4 q0, float4 q1,
                                      float4 q2, float4 q3) {
  A[0]  = fmaf(p, q0.x, A[0]);  A[1]  = fmaf(p, q0.y, A[1]);
  A[2]  = fmaf(p, q0.z, A[2]);  A[3]  = fmaf(p, q0.w, A[3]);
  A[4]  = fmaf(p, q1.x, A[4]);  A[5]  = fmaf(p, q1.y, A[5]);
  A[6]  = fmaf(p, q1.z, A[6]);  A[7]  = fmaf(p, q1.w, A[7]);
  A[8]  = fmaf(p, q2.x, A[8]);  A[9]  = fmaf(p, q2.y, A[9]);
  A[10] = fmaf(p, q2.z, A[10]); A[11] = fmaf(p, q2.w, A[11]);
  A[12] = fmaf(p, q3.x, A[12]); A[13] = fmaf(p, q3.y, A[13]);
  A[14] = fmaf(p, q3.z, A[14]); A[15] = fmaf(p, q3.w, A[15]);
}

// ---------------- Kernel 1: weighted Gram reduction (2x3 tile, LDS phi) ----------------
__global__ __launch_bounds__(256, 3)
void gram_reduce(const float* __restrict__ Phi, const float* __restrict__ Xd,
                 const float* __restrict__ Yd, const float* __restrict__ Welm,
                 const float* __restrict__ belm, float* __restrict__ slabs)
{
  __shared__ float sW[Dd * Hh];
  __shared__ float sb[Hh];
  __shared__ float Xs[NB][XSD];
  __shared__ __align__(16) float Ps[NB][PSD];  // phi tile, stride 80B (bank de-alias)

  int tid = threadIdx.x;
  for (int i = tid; i < Dd * Hh; i += 256) sW[i] = Welm[i];
  if (tid < Hh) sb[tid] = belm[tid];

  // ---- decode thread -> 2x3 tile (rp: row-pair 0..24, cq: col-triple) ----
  int rp = -1, cq = 0;
  {
    int c = 0;
    for (int r = 0; r < 25; ++r) {
      int cmin = (2 * r) / 3;
      int cnt = 17 - cmin;          // cq in [cmin, 17)
      if (rp < 0 && tid < c + cnt) { rp = r; cq = cmin + (tid - c); }
      c += cnt;
    }
    if (tid >= c) rp = -1;          // 233 active threads
  }
  bool active = (rp >= 0);
  int r0 = 2 * rp, r1 = 2 * rp + 1;
  int c0 = 3 * cq, c1 = 3 * cq + 1, c2 = 3 * cq + 2;
  if (!active) { r0 = r1 = 0; c0 = c1 = c2 = 0; }

  v16f A00 = {}, A01 = {}, A02 = {}, A10 = {}, A11 = {}, A12 = {};

  for (int tile = blockIdx.x; tile < NTILES; tile += gridDim.x) {
    int n0 = tile * NB;
    __syncthreads();  // protect Xs/Ps from prior iteration readers
    // stage phi (coalesced float4 copy; row stride 20 floats)
    for (int idx = tid; idx < NB * 4; idx += 256) {
      int n = idx >> 2, q = idx & 3;
      int gn = n0 + n;
      ((float4*)&Ps[n][0])[q] = (gn < Nn)
        ? ((const float4*)(Phi + (size_t)gn * Tt))[q]
        : make_float4(0.f, 0.f, 0.f, 0.f);
    }
    // stage x
    for (int idx = tid; idx < NB * Dd; idx += 256) {
      int n = idx / Dd, d = idx % Dd;
      int gn = n0 + n;
      Xs[n][41 + d] = (gn < Nn) ? Xd[gn * Dd + d] : 0.f;
    }
    // stage y + const col + pad col
    for (int n = tid; n < NB; n += 256) {
      int gn = n0 + n;
      Xs[n][49] = (gn < Nn) ? Yd[gn] : 0.f;
      Xs[n][40] = (gn < Nn) ? 1.f : 0.f;
      Xs[n][50] = 0.f;
    }
    __syncthreads();
    // ELM hidden layer: h = sigmoid(x W + b); zero for pad rows
    for (int idx = tid; idx < NB * Hh; idx += 256) {
      int n = idx / Hh, h = idx % Hh;
      float z = sb[h];
#pragma unroll
      for (int d = 0; d < Dd; ++d) z += Xs[n][41 + d] * sW[d * Hh + h];
      float s = 1.f / (1.f + __expf(-z));
      Xs[n][h] = (n0 + n < Nn) ? s : 0.f;
    }
    __syncthreads();
    // accumulate: A[r][c][t] += phi[n][t] * Xe[n][r] * Xe[n][c]
    if (active) {
#pragma unroll 2
      for (int n = 0; n < NB; ++n) {
        const float4* pr = (const float4*)&Ps[n][0];   // LDS broadcast b128 x4
        float4 q0 = pr[0], q1 = pr[1], q2 = pr[2], q3 = pr[3];
        float xi0 = Xs[n][r0], xi1 = Xs[n][r1];
        float xj0 = Xs[n][c0], xj1 = Xs[n][c1], xj2 = Xs[n][c2];
        fma16(A00, xi0 * xj0, q0, q1, q2, q3);
        fma16(A01, xi0 * xj1, q0, q1, q2, q3);
        fma16(A02, xi0 * xj2, q0, q1, q2, q3);
        fma16(A10, xi1 * xj0, q0, q1, q2, q3);
        fma16(A11, xi1 * xj1, q0, q1, q2, q3);
        fma16(A12, xi1 * xj2, q0, q1, q2, q3);
      }
    }
  }
  // flush: 64B vector store per upper-triangle pair
  float* slab = slabs + (size_t)blockIdx.x * SLAB;
  if (active) {
    if (c0 >= r0 && c0 < 50) *(v16f*)(slab + pidx(r0, c0) * Tt) = A00;
    if (c1 >= r0 && c1 < 50) *(v16f*)(slab + pidx(r0, c1) * Tt) = A01;
    if (c2 >= r0 && c2 < 50) *(v16f*)(slab + pidx(r0, c2) * Tt) = A02;
    if (c0 >= r1 && c0 < 50) *(v16f*)(slab + pidx(r1, c0) * Tt) = A10;
    if (c1 >= r1 && c1 < 50) *(v16f*)(slab + pidx(r1, c1) * Tt) = A11;
    if (c2 >= r1 && c2 < 50) *(v16f*)(slab + pidx(r1, c2) * Tt) = A12;
  }
}

// ---------------- Kernel 1b: two-stage slab reduction, float4 ----------------
__global__ __launch_bounds__(256)
void reduce_slabs_a(const float4* __restrict__ slabs4, int nslabs,
                    float4* __restrict__ part4)
{
  int g = blockIdx.y;
  int idx = blockIdx.x * 256 + threadIdx.x;   // 20 blocks cover SLAB/4 = 5120
  int b0 = g * SLABGRP;
  int b1 = b0 + SLABGRP; if (b1 > nslabs) b1 = nslabs;
  float4 s = make_float4(0.f, 0.f, 0.f, 0.f);
  for (int b = b0; b < b1; ++b) {
    float4 v = slabs4[(size_t)b * (SLAB / 4) + idx];
    s.x += v.x; s.y += v.y; s.z += v.z; s.w += v.w;
  }
  part4[(size_t)g * (SLAB / 4) + idx] = s;
}

__global__ __launch_bounds__(256)
void reduce_slabs_b(const float4* __restrict__ part4, int ngrp,
                    float4* __restrict__ accout4)
{
  int idx = blockIdx.x * 256 + threadIdx.x;   // 20 blocks
  float4 s = make_float4(0.f, 0.f, 0.f, 0.f);
  for (int g = 0; g < ngrp; ++g) {
    float4 v = part4[(size_t)g * (SLAB / 4) + idx];
    s.x += v.x; s.y += v.y; s.z += v.z; s.w += v.w;
  }
  accout4[idx] = s;
}

// ---------------- Kernel 2: block-parallel compact LDS GJ (R16-proven); t1 from Gram ----------------
__global__ __launch_bounds__(256)
void finalize_kernel(const float* __restrict__ acc, const float* __restrict__ epsA,
                     const float* __restrict__ epsB, const float* __restrict__ zetA,
                     const float* __restrict__ zetB, float* __restrict__ out)
{
  int t = blockIdx.x;
  int tid = threadIdx.x;
  __shared__ float G[HP1][84];          // [M | I] augmented
  __shared__ float As[HP1][HP1 + 1];
  __shared__ float bs[HP1];
  __shared__ float colk[HP1];
  __shared__ float red[256];
  __shared__ float wmv[HP1];
  __shared__ float rowv[4][HP1 + 1];    // per-row partials: wb, wn, trc, quad
  __shared__ float mus[Dd];

  float epsExp = epsA[t] / epsB[t];
  float zetaExp = zetA[t] / zetB[t];

  for (int idx = tid; idx < HP1 * HP1; idx += 256) {
    int i = idx / HP1, j = idx % HP1;
    float a = acc[pidx(i, j) * Tt + t];
    As[i][j] = a;
    G[i][j] = epsExp * a + (i == j ? zetaExp : 0.f);
    G[i][41 + j] = (i == j) ? 1.f : 0.f;
  }
  for (int idx = tid; idx < HP1; idx += 256) {
    G[idx][82] = 0.f; G[idx][83] = 0.f;
    bs[idx] = acc[pidx(idx, 49) * Tt + t];
  }
  __syncthreads();

  // compact Gauss-Jordan: 2 barriers / pivot
  for (int k = 0; k < HP1; ++k) {
    float pivinv = 1.f / G[k][k];       // broadcast LDS read (stable since barrier)
    // scale pivot row over active cols k+1..k+41 (tid=1..41); extract column k
    if (tid >= 1 && tid <= HP1) G[k][k + tid] *= pivinv;   // 41 cols incl. k+41!
    if (tid < HP1) colk[tid] = (tid == k) ? 0.f : G[tid][k];
    __syncthreads();
    // rank-1 update: rows 0..40 x cols k+1..k+41 (1681 elems)
    for (int idx = tid; idx < HP1 * HP1; idx += 256) {
      int i = idx / HP1, c = idx % HP1;
      int j = k + 1 + c;
      G[i][j] = fmaf(-colk[i], G[k][j], G[i][j]);
    }
    __syncthreads();
  }

  // write WS (inverse at cols 41..81)
  for (int idx = tid; idx < HP1 * HP1; idx += 256) {
    int i = idx / HP1, j = idx % HP1;
    out[OFF_WS + (t * HP1 + i) * HP1 + j] = G[i][41 + j];
  }
  // WMv = zetaExp * WS @ b
  if (tid < HP1) {
    float s = 0.f;
    for (int j = 0; j < HP1; ++j) s += G[tid][41 + j] * bs[j];
    float w = zetaExp * s;
    wmv[tid] = w;
    out[OFF_WM + t * HP1 + tid] = w;
  }
  __syncthreads();
  // t2 = sum_ij A_ij WS_ij (256-thread reduction)
  float lt2 = 0.f;
  for (int idx = tid; idx < HP1 * HP1; idx += 256) {
    int i = idx / HP1, j = idx % HP1;
    lt2 += As[i][j] * G[i][41 + j];
  }
  red[tid] = lt2; __syncthreads();
  for (int s = 128; s > 0; s >>= 1) {
    if (tid < s) red[tid] += red[tid + s];
    __syncthreads();
  }
  float t2v = red[0];
  // per-row scalars: wb, wn, trc, quad
  if (tid < HP1) {
    float w = wmv[tid];
    float aw = 0.f;
    for (int j = 0; j < HP1; ++j) aw += As[tid][j] * wmv[j];
    rowv[0][tid] = w * bs[tid];
    rowv[1][tid] = w * w;
    rowv[2][tid] = G[tid][41 + tid];
    rowv[3][tid] = w * aw;
  }
  __syncthreads();

  float sp = acc[pidx(40, 40) * Tt + t];   // sumPhi[t]
  float kap = 1000.f + sp;
  float syy = acc[pidx(49, 49) * Tt + t];  // sum phi y^2

  if (tid == 0) {
    float wb = 0.f, wn = 0.f, trc = 0.f, quad = 0.f;
    for (int i = 0; i < HP1; ++i) {
      wb += rowv[0][i]; wn += rowv[1][i]; trc += rowv[2][i]; quad += rowv[3][i];
    }
    float t1 = syy - 2.f * wb + quad;      // sum_n phi*(y-pred)^2, from Gram
    out[OFF_BG1 + t] = 1.f + sp;
    float rest = 0.f;
    for (int u = t + 1; u < Tt; ++u) rest += acc[pidx(40, 40) * Tt + u];
    out[OFF_BG2 + t] = 1.f + rest;            // ALPHA_DP = 1
    out[OFF_KAPPA + t] = kap;
    out[OFF_NU + t] = sp + 100.f;             // sumPhi + NU0
    out[OFF_ZA + t] = zetA[t] + 0.5f * (float)HP1;
    out[OFF_ZB + t] = zetB[t] + 0.5f * (wn + trc);
    out[OFF_EA + t] = epsA[t] + 0.5f * sp;
    out[OFF_EB + t] = epsB[t] + 0.5f * (t1 + t2v);
  }
  // mu
  if (tid < Dd) {
    float m = acc[pidx(40, 41 + tid) * Tt + t] / kap;
    mus[tid] = m;
    out[OFF_MU + tid * Tt + t] = m;
  }
  __syncthreads();
  // psi = 500*I + S - kappa * mu mu^T
  if (tid < Dd * Dd) {
    int i = tid / Dd, j = tid % Dd;
    float S = acc[pidx(41 + i, 41 + j) * Tt + t];
    float v = (i == j ? 500.f : 0.f) + S - kap * mus[i] * mus[j];
    out[OFF_PSI + (i * Dd + j) * Tt + t] = v;
  }
}

extern "C" void kernel_launch(void* const* d_in, const int* in_sizes, int n_in,
                              void* d_out, int out_size, void* d_ws, size_t ws_size,
                              hipStream_t stream) {
  const float* Phi = (const float*)d_in[1];
  const float* Xd  = (const float*)d_in[2];
  const float* Yd  = (const float*)d_in[3];
  const float* W   = (const float*)d_in[4];
  const float* bb  = (const float*)d_in[5];
  const float* eA  = (const float*)d_in[6];
  const float* eB  = (const float*)d_in[7];
  const float* zA  = (const float*)d_in[8];
  const float* zB  = (const float*)d_in[9];
  float* out = (float*)d_out;
  float* ws  = (float*)d_ws;

  float* acc_red = ws + WS_ACC;
  float* part    = ws + WS_PART;
  float* slabs   = ws + WS_SLB;

  // slab count bounded by available scratch (deterministic, graph-safe)
  long avail = (long)(ws_size / 4) - WS_SLB;
  int grid1 = (int)(avail / SLAB);
  if (grid1 > NTILES) grid1 = NTILES;       // 782: one tile per block
  if (grid1 > MAXSLABS) grid1 = MAXSLABS;
  if (grid1 < 1) grid1 = 1;
  int ngrp = (grid1 + SLABGRP - 1) / SLABGRP;

  hipLaunchKernelGGL(gram_reduce, dim3(grid1), dim3(256), 0, stream, Phi, Xd, Yd, W, bb, slabs);
  hipLaunchKernelGGL(reduce_slabs_a, dim3(SLAB / 4 / 256, ngrp), dim3(256), 0, stream,
                     (const float4*)slabs, grid1, (float4*)part);
  hipLaunchKernelGGL(reduce_slabs_b, dim3(SLAB / 4 / 256), dim3(256), 0, stream,
                     (const float4*)part, ngrp, (float4*)acc_red);
  hipLaunchKernelGGL(finalize_kernel, dim3(Tt), dim3(256), 0, stream, acc_red, eA, eB, zA, zB, out);
}

// Round 19
// 204.779 us; speedup vs baseline: 1.0653x; 1.0653x over previous
//
#include <hip/hip_runtime.h>

#define Nn 100000
#define Tt 16
#define Dd 8
#define Hh 40
#define HP1 41
#define XSD 51     // Xs row: [h0..h39, 1, x0..x7, y, 0pad] stride 51
#define PSD 16     // Ps row stride (floats)
#define NPAIR 1275 // 50*51/2 symmetric pairs (i,j in [0,50))
#define NB 128
#define NTILES ((Nn + NB - 1) / NB)   // 782
#define SLAB 20480           // floats per block-slab (NPAIR*16 = 20400, padded)
#define MAXSLABS 784
#define SLABGRP 64           // slabs per stage-A group
#define MAXGRP ((MAXSLABS + SLABGRP - 1) / SLABGRP)   // 13
#define WS_ACC 0             // acc_red: 20480 floats
#define WS_PART 21504        // stage-A partials: MAXGRP * SLAB floats
#define WS_SLB (WS_PART + MAXGRP * SLAB)              // slabs start here

// output offsets (flat, return order)
#define OFF_BG1   0
#define OFF_BG2   16
#define OFF_MU    32
#define OFF_KAPPA 160
#define OFF_NU    176
#define OFF_PSI   192
#define OFF_WM    1216
#define OFF_WS    1872
#define OFF_ZA    28768
#define OFF_ZB    28784
#define OFF_EA    28800
#define OFF_EB    28816

typedef float v16f __attribute__((ext_vector_type(16)));

__device__ __forceinline__ int pidx(int i, int j) {
  if (i > j) { int tmp = i; i = j; j = tmp; }
  return (i * (2 * 50 - i + 1)) / 2 + (j - i);
}

__device__ __forceinline__ void fma16(v16f& A, float p, float4 q0, float4 q1,
                                      float4 q2, float4 q3) {
  A[0]  = fmaf(p, q0.x, A[0]);  A[1]  = fmaf(p, q0.y, A[1]);
  A[2]  = fmaf(p, q0.z, A[2]);  A[3]  = fmaf(p, q0.w, A[3]);
  A[4]  = fmaf(p, q1.x, A[4]);  A[5]  = fmaf(p, q1.y, A[5]);
  A[6]  = fmaf(p, q1.z, A[6]);  A[7]  = fmaf(p, q1.w, A[7]);
  A[8]  = fmaf(p, q2.x, A[8]);  A[9]  = fmaf(p, q2.y, A[9]);
  A[10] = fmaf(p, q2.z, A[10]); A[11] = fmaf(p, q2.w, A[11]);
  A[12] = fmaf(p, q3.x, A[12]); A[13] = fmaf(p, q3.y, A[13]);
  A[14] = fmaf(p, q3.z, A[14]); A[15] = fmaf(p, q3.w, A[15]);
}

// ---------------- Kernel 1: weighted Gram reduction (2x3 tile, LDS phi) ----------------
__global__ __launch_bounds__(256, 3)
void gram_reduce(const float* __restrict__ Phi, const float* __restrict__ Xd,
                 const float* __restrict__ Yd, const float* __restrict__ Welm,
                 const float* __restrict__ belm, float* __restrict__ slabs)
{
  __shared__ float sW[Dd * Hh];
  __shared__ float sb[Hh];
  __shared__ float Xs[NB][XSD];
  __shared__ __align__(16) float Ps[NB][PSD];  // phi tile, row = 64B

  int tid = threadIdx.x;
  for (int i = tid; i < Dd * Hh; i += 256) sW[i] = Welm[i];
  if (tid < Hh) sb[tid] = belm[tid];

  // ---- decode thread -> 2x3 tile (rp: row-pair 0..24, cq: col-triple) ----
  int rp = -1, cq = 0;
  {
    int c = 0;
    for (int r = 0; r < 25; ++r) {
      int cmin = (2 * r) / 3;
      int cnt = 17 - cmin;          // cq in [cmin, 17)
      if (rp < 0 && tid < c + cnt) { rp = r; cq = cmin + (tid - c); }
      c += cnt;
    }
    if (tid >= c) rp = -1;          // 233 active threads
  }
  bool active = (rp >= 0);
  int r0 = 2 * rp, r1 = 2 * rp + 1;
  int c0 = 3 * cq, c1 = 3 * cq + 1, c2 = 3 * cq + 2;
  if (!active) { r0 = r1 = 0; c0 = c1 = c2 = 0; }

  v16f A00 = {}, A01 = {}, A02 = {}, A10 = {}, A11 = {}, A12 = {};

  for (int tile = blockIdx.x; tile < NTILES; tile += gridDim.x) {
    int n0 = tile * NB;
    __syncthreads();  // protect Xs/Ps from prior iteration readers
    // stage phi (coalesced float4 copy; layout matches global)
    for (int idx = tid; idx < NB * 4; idx += 256) {
      int n = idx >> 2, q = idx & 3;
      int gn = n0 + n;
      ((float4*)&Ps[n][0])[q] = (gn < Nn)
        ? ((const float4*)(Phi + (size_t)gn * Tt))[q]
        : make_float4(0.f, 0.f, 0.f, 0.f);
    }
    // stage x
    for (int idx = tid; idx < NB * Dd; idx += 256) {
      int n = idx / Dd, d = idx % Dd;
      int gn = n0 + n;
      Xs[n][41 + d] = (gn < Nn) ? Xd[gn * Dd + d] : 0.f;
    }
    // stage y + const col + pad col
    for (int n = tid; n < NB; n += 256) {
      int gn = n0 + n;
      Xs[n][49] = (gn < Nn) ? Yd[gn] : 0.f;
      Xs[n][40] = (gn < Nn) ? 1.f : 0.f;
      Xs[n][50] = 0.f;
    }
    __syncthreads();
    // ELM hidden layer: h = sigmoid(x W + b); zero for pad rows
    for (int idx = tid; idx < NB * Hh; idx += 256) {
      int n = idx / Hh, h = idx % Hh;
      float z = sb[h];
#pragma unroll
      for (int d = 0; d < Dd; ++d) z += Xs[n][41 + d] * sW[d * Hh + h];
      float s = 1.f / (1.f + __expf(-z));
      Xs[n][h] = (n0 + n < Nn) ? s : 0.f;
    }
    __syncthreads();
    // accumulate: A[r][c][t] += phi[n][t] * Xe[n][r] * Xe[n][c]
    if (active) {
#pragma unroll 2
      for (int n = 0; n < NB; ++n) {
        const float4* pr = (const float4*)&Ps[n][0];   // LDS broadcast b128 x4
        float4 q0 = pr[0], q1 = pr[1], q2 = pr[2], q3 = pr[3];
        float xi0 = Xs[n][r0], xi1 = Xs[n][r1];
        float xj0 = Xs[n][c0], xj1 = Xs[n][c1], xj2 = Xs[n][c2];
        fma16(A00, xi0 * xj0, q0, q1, q2, q3);
        fma16(A01, xi0 * xj1, q0, q1, q2, q3);
        fma16(A02, xi0 * xj2, q0, q1, q2, q3);
        fma16(A10, xi1 * xj0, q0, q1, q2, q3);
        fma16(A11, xi1 * xj1, q0, q1, q2, q3);
        fma16(A12, xi1 * xj2, q0, q1, q2, q3);
      }
    }
  }
  // flush: 64B vector store per upper-triangle pair
  float* slab = slabs + (size_t)blockIdx.x * SLAB;
  if (active) {
    if (c0 >= r0 && c0 < 50) *(v16f*)(slab + pidx(r0, c0) * Tt) = A00;
    if (c1 >= r0 && c1 < 50) *(v16f*)(slab + pidx(r0, c1) * Tt) = A01;
    if (c2 >= r0 && c2 < 50) *(v16f*)(slab + pidx(r0, c2) * Tt) = A02;
    if (c0 >= r1 && c0 < 50) *(v16f*)(slab + pidx(r1, c0) * Tt) = A10;
    if (c1 >= r1 && c1 < 50) *(v16f*)(slab + pidx(r1, c1) * Tt) = A11;
    if (c2 >= r1 && c2 < 50) *(v16f*)(slab + pidx(r1, c2) * Tt) = A12;
  }
}

// ---------------- Kernel 1b: two-stage slab reduction, float4 ----------------
__global__ __launch_bounds__(256)
void reduce_slabs_a(const float4* __restrict__ slabs4, int nslabs,
                    float4* __restrict__ part4)
{
  int g = blockIdx.y;
  int idx = blockIdx.x * 256 + threadIdx.x;   // 20 blocks cover SLAB/4 = 5120
  int b0 = g * SLABGRP;
  int b1 = b0 + SLABGRP; if (b1 > nslabs) b1 = nslabs;
  float4 s = make_float4(0.f, 0.f, 0.f, 0.f);
  for (int b = b0; b < b1; ++b) {
    float4 v = slabs4[(size_t)b * (SLAB / 4) + idx];
    s.x += v.x; s.y += v.y; s.z += v.z; s.w += v.w;
  }
  part4[(size_t)g * (SLAB / 4) + idx] = s;
}

__global__ __launch_bounds__(256)
void reduce_slabs_b(const float4* __restrict__ part4, int ngrp,
                    float4* __restrict__ accout4)
{
  int idx = blockIdx.x * 256 + threadIdx.x;   // 20 blocks
  float4 s = make_float4(0.f, 0.f, 0.f, 0.f);
  for (int g = 0; g < ngrp; ++g) {
    float4 v = part4[(size_t)g * (SLAB / 4) + idx];
    s.x += v.x; s.y += v.y; s.z += v.z; s.w += v.w;
  }
  accout4[idx] = s;
}

// ---------------- Kernel 2: block-parallel compact LDS GJ; t1 from Gram ----------------
// 16 blocks x 256 threads. Column-per-thread rank-1 update: thread owns col
// j = k+1+c for a 7-row group; pivot value pk cached in a register.
__global__ __launch_bounds__(256)
void finalize_kernel(const float* __restrict__ acc, const float* __restrict__ epsA,
                     const float* __restrict__ epsB, const float* __restrict__ zetA,
                     const float* __restrict__ zetB, float* __restrict__ out)
{
  int t = blockIdx.x;
  int tid = threadIdx.x;
  __shared__ float G[HP1][84];          // [M | I] augmented
  __shared__ float As[HP1][HP1 + 1];
  __shared__ float bs[HP1];
  __shared__ float colk[HP1];
  __shared__ float red[256];
  __shared__ float wmv[HP1];
  __shared__ float rowv[4][HP1 + 1];    // per-row partials: wb, wn, trc, quad
  __shared__ float mus[Dd];

  float epsExp = epsA[t] / epsB[t];
  float zetaExp = zetA[t] / zetB[t];

  for (int idx = tid; idx < HP1 * HP1; idx += 256) {
    int i = idx / HP1, j = idx % HP1;
    float a = acc[pidx(i, j) * Tt + t];
    As[i][j] = a;
    G[i][j] = epsExp * a + (i == j ? zetaExp : 0.f);
    G[i][41 + j] = (i == j) ? 1.f : 0.f;
  }
  for (int idx = tid; idx < HP1; idx += 256) {
    G[idx][82] = 0.f; G[idx][83] = 0.f;
    bs[idx] = acc[pidx(idx, 49) * Tt + t];
  }
  __syncthreads();

  // column-per-thread decode: c = col offset, ig = 7-row group (ig<6 active)
  int c = tid % HP1;         // 0..40
  int ig = tid / HP1;        // 0..6; use ig<6 (threads 0..245)
  int irow0 = ig * 7;        // rows irow0..irow0+6 (covers 0..41, guard i<41)

  // compact Gauss-Jordan: 2 barriers / pivot
  for (int k = 0; k < HP1; ++k) {
    float pivinv = 1.f / G[k][k];       // broadcast LDS read (stable since barrier)
    // scale pivot row over active cols k+1..k+41 (tid=1..41); extract column k
    if (tid >= 1 && tid <= HP1) G[k][k + tid] *= pivinv;   // 41 cols incl. k+41
    if (tid < HP1) colk[tid] = (tid == k) ? 0.f : G[tid][k];
    __syncthreads();
    // rank-1 update: col j = k+1+c, rows irow0..irow0+6; pk cached
    if (ig < 6) {
      int j = k + 1 + c;
      float pk = G[k][j];
#pragma unroll
      for (int r = 0; r < 7; ++r) {
        int i = irow0 + r;
        if (i < HP1 && i != k) G[i][j] = fmaf(-colk[i], pk, G[i][j]);
      }
    }
    __syncthreads();
  }

  // write WS (inverse at cols 41..81)
  for (int idx = tid; idx < HP1 * HP1; idx += 256) {
    int i = idx / HP1, j = idx % HP1;
    out[OFF_WS + (t * HP1 + i) * HP1 + j] = G[i][41 + j];
  }
  // WMv = zetaExp * WS @ b
  if (tid < HP1) {
    float s = 0.f;
    for (int j = 0; j < HP1; ++j) s += G[tid][41 + j] * bs[j];
    float w = zetaExp * s;
    wmv[tid] = w;
    out[OFF_WM + t * HP1 + tid] = w;
  }
  __syncthreads();
  // t2 = sum_ij A_ij WS_ij (256-thread reduction)
  float lt2 = 0.f;
  for (int idx = tid; idx < HP1 * HP1; idx += 256) {
    int i = idx / HP1, j = idx % HP1;
    lt2 += As[i][j] * G[i][41 + j];
  }
  red[tid] = lt2; __syncthreads();
  for (int s = 128; s > 0; s >>= 1) {
    if (tid < s) red[tid] += red[tid + s];
    __syncthreads();
  }
  float t2v = red[0];
  // per-row scalars: wb, wn, trc, quad
  if (tid < HP1) {
    float w = wmv[tid];
    float aw = 0.f;
    for (int j = 0; j < HP1; ++j) aw += As[tid][j] * wmv[j];
    rowv[0][tid] = w * bs[tid];
    rowv[1][tid] = w * w;
    rowv[2][tid] = G[tid][41 + tid];
    rowv[3][tid] = w * aw;
  }
  __syncthreads();

  float sp = acc[pidx(40, 40) * Tt + t];   // sumPhi[t]
  float kap = 1000.f + sp;
  float syy = acc[pidx(49, 49) * Tt + t];  // sum phi y^2

  if (tid == 0) {
    float wb = 0.f, wn = 0.f, trc = 0.f, quad = 0.f;
    for (int i = 0; i < HP1; ++i) {
      wb += rowv[0][i]; wn += rowv[1][i]; trc += rowv[2][i]; quad += rowv[3][i];
    }
    float t1 = syy - 2.f * wb + quad;      // sum_n phi*(y-pred)^2, from Gram
    out[OFF_BG1 + t] = 1.f + sp;
    float rest = 0.f;
    for (int u = t + 1; u < Tt; ++u) rest += acc[pidx(40, 40) * Tt + u];
    out[OFF_BG2 + t] = 1.f + rest;            // ALPHA_DP = 1
    out[OFF_KAPPA + t] = kap;
    out[OFF_NU + t] = sp + 100.f;             // sumPhi + NU0
    out[OFF_ZA + t] = zetA[t] + 0.5f * (float)HP1;
    out[OFF_ZB + t] = zetB[t] + 0.5f * (wn + trc);
    out[OFF_EA + t] = epsA[t] + 0.5f * sp;
    out[OFF_EB + t] = epsB[t] + 0.5f * (t1 + t2v);
  }
  // mu
  if (tid < Dd) {
    float m = acc[pidx(40, 41 + tid) * Tt + t] / kap;
    mus[tid] = m;
    out[OFF_MU + tid * Tt + t] = m;
  }
  __syncthreads();
  // psi = 500*I + S - kappa * mu mu^T
  if (tid < Dd * Dd) {
    int i = tid / Dd, j = tid % Dd;
    float S = acc[pidx(41 + i, 41 + j) * Tt + t];
    float v = (i == j ? 500.f : 0.f) + S - kap * mus[i] * mus[j];
    out[OFF_PSI + (i * Dd + j) * Tt + t] = v;
  }
}

extern "C" void kernel_launch(void* const* d_in, const int* in_sizes, int n_in,
                              void* d_out, int out_size, void* d_ws, size_t ws_size,
                              hipStream_t stream) {
  const float* Phi = (const float*)d_in[1];
  const float* Xd  = (const float*)d_in[2];
  const float* Yd  = (const float*)d_in[3];
  const float* W   = (const float*)d_in[4];
  const float* bb  = (const float*)d_in[5];
  const float* eA  = (const float*)d_in[6];
  const float* eB  = (const float*)d_in[7];
  const float* zA  = (const float*)d_in[8];
  const float* zB  = (const float*)d_in[9];
  float* out = (float*)d_out;
  float* ws  = (float*)d_ws;

  float* acc_red = ws + WS_ACC;
  float* part    = ws + WS_PART;
  float* slabs   = ws + WS_SLB;

  // slab count bounded by available scratch (deterministic, graph-safe)
  long avail = (long)(ws_size / 4) - WS_SLB;
  int grid1 = (int)(avail / SLAB);
  if (grid1 > NTILES) grid1 = NTILES;       // 782: one tile per block
  if (grid1 > MAXSLABS) grid1 = MAXSLABS;
  if (grid1 < 1) grid1 = 1;
  int ngrp = (grid1 + SLABGRP - 1) / SLABGRP;

  hipLaunchKernelGGL(gram_reduce, dim3(grid1), dim3(256), 0, stream, Phi, Xd, Yd, W, bb, slabs);
  hipLaunchKernelGGL(reduce_slabs_a, dim3(SLAB / 4 / 256, ngrp), dim3(256), 0, stream,
                     (const float4*)slabs, grid1, (float4*)part);
  hipLaunchKernelGGL(reduce_slabs_b, dim3(SLAB / 4 / 256), dim3(256), 0, stream,
                     (const float4*)part, ngrp, (float4*)acc_red);
  hipLaunchKernelGGL(finalize_kernel, dim3(Tt), dim3(256), 0, stream, acc_red, eA, eB, zA, zB, out);
}